// Round 5
// baseline (2956.209 us; speedup 1.0000x reference)
//
#include <hip/hip_runtime.h>

#define NNODES 100000
#define NEDGES 600000
#define NGRAPH 64
#define HID 128
#define RHD 500
#define NB ((NNODES + 255) / 256)            // 391
#define EB ((NEDGES + 255) / 256)            // 2344
#define GB ((NNODES + 255) / 256)            // gemm row-blocks (256 rows each) = 391

__device__ __forceinline__ float leaky1(float x) { return x >= 0.0f ? x : 0.01f * x; }

// ================= CSR build (deterministic) =================
__global__ __launch_bounds__(256) void hist_kernel(
    const int* __restrict__ ei, int* __restrict__ deg)
{
    int e = blockIdx.x * 256 + threadIdx.x;
    if (e < NEDGES) atomicAdd(&deg[ei[NEDGES + e]], 1);
}

__global__ __launch_bounds__(256) void scan_blk(
    const int* __restrict__ deg, int* __restrict__ incl, int* __restrict__ bsum)
{
    __shared__ int s[256];
    int t = threadIdx.x;
    int n = blockIdx.x * 256 + t;
    int v = (n < NNODES) ? deg[n] : 0;
    int x = v;
    s[t] = x;
    __syncthreads();
    for (int off = 1; off < 256; off <<= 1) {
        int y = (t >= off) ? s[t - off] : 0;
        __syncthreads();
        x += y; s[t] = x;
        __syncthreads();
    }
    if (n < NNODES) incl[n] = x;
    if (t == 255) bsum[blockIdx.x] = x;
}

__global__ __launch_bounds__(512) void scan_bsum(int* __restrict__ bsum, int nblk)
{
    __shared__ int s[512];
    int t = threadIdx.x;
    int v = (t < nblk) ? bsum[t] : 0;
    int x = v;
    s[t] = x;
    __syncthreads();
    for (int off = 1; off < 512; off <<= 1) {
        int y = (t >= off) ? s[t - off] : 0;
        __syncthreads();
        x += y; s[t] = x;
        __syncthreads();
    }
    if (t < nblk) bsum[t] = x - v;   // exclusive
}

__global__ __launch_bounds__(256) void finalize_rp(
    const int* __restrict__ deg, const int* __restrict__ bsum,
    int* __restrict__ rp, int* __restrict__ cursor)
{
    int n = blockIdx.x * 256 + threadIdx.x;
    if (n >= NNODES) return;
    int ig = rp[n] + bsum[blockIdx.x];   // global inclusive
    int st = ig - deg[n];
    rp[n] = st;
    cursor[n] = st;
    if (n == NNODES - 1) rp[NNODES] = ig;
}

__global__ __launch_bounds__(256) void scatter_kernel(
    const int* __restrict__ ei, int* __restrict__ cursor, int* __restrict__ eid)
{
    int e = blockIdx.x * 256 + threadIdx.x;
    if (e >= NEDGES) return;
    int d = ei[NEDGES + e];
    int pos = atomicAdd(&cursor[d], 1);
    eid[pos] = e;
}

__global__ __launch_bounds__(256) void seg_sort(
    const int* __restrict__ rp, int* __restrict__ eid)
{
    int n = blockIdx.x * 256 + threadIdx.x;
    if (n >= NNODES) return;
    int beg = rp[n], end = rp[n + 1];
    for (int i = beg + 1; i < end; ++i) {
        int key = eid[i];
        int j = i - 1;
        while (j >= beg && eid[j] > key) { eid[j + 1] = eid[j]; --j; }
        eid[j + 1] = key;
    }
}

__global__ __launch_bounds__(256) void permute_kernel(
    const int* __restrict__ eid, const int* __restrict__ ei,
    const float* __restrict__ ea, int* __restrict__ srcp, float* __restrict__ eap)
{
    int p = blockIdx.x * 256 + threadIdx.x;
    if (p >= NEDGES) return;
    int id = eid[p];
    srcp[p] = ei[id];
    const float* s = ea + (size_t)id * 7;
    float* d = eap + (size_t)p * 7;
#pragma unroll
    for (int k = 0; k < 7; ++k) d[k] = s[k];
}

// ================= layer 0 aggregate (d=2) =================
__global__ __launch_bounds__(256) void aggregate0_kernel(
    const float* __restrict__ x, const int* __restrict__ rp,
    const int* __restrict__ srcp, const float* __restrict__ eap,
    const float* __restrict__ ew, const float* __restrict__ eb,
    float* __restrict__ aggr2)
{
    int n = blockIdx.x * 256 + threadIdx.x;
    if (n >= NNODES) return;
    float w0[7], w1[7];
#pragma unroll
    for (int k = 0; k < 7; ++k) { w0[k] = ew[k]; w1[k] = ew[7 + k]; }
    float e0b = eb[0], e1b = eb[1];
    float a0 = x[n * 2 + 0], a1 = x[n * 2 + 1];
    int beg = rp[n], end = rp[n + 1];
    for (int e = beg; e < end; ++e) {
        int s = srcp[e];
        const float* ap = eap + (size_t)e * 7;
        float t0 = e0b, t1 = e1b;
#pragma unroll
        for (int k = 0; k < 7; ++k) {
            float av = ap[k];
            t0 = fmaf(av, w0[k], t0);
            t1 = fmaf(av, w1[k], t1);
        }
        a0 += fmaxf(x[s * 2 + 0] + t0, 0.0f);
        a1 += fmaxf(x[s * 2 + 1] + t1, 0.0f);
    }
    aggr2[n * 2 + 0] = a0;
    aggr2[n * 2 + 1] = a1;
}

// ================= hidden aggregate (d=128): one wave per 8 nodes =================
__global__ __launch_bounds__(256) void aggregate_kernel(
    const float* __restrict__ hin, const int* __restrict__ rp,
    const int* __restrict__ srcp, const float* __restrict__ eap,
    const float* __restrict__ ew, const float* __restrict__ eb,
    float* __restrict__ A)
{
    int lane = threadIdx.x & 63;
    int w = threadIdx.x >> 6;
    int nbase = blockIdx.x * 32 + w * 8;
    float ew0[7], ew1[7];
#pragma unroll
    for (int k = 0; k < 7; ++k) {
        ew0[k] = ew[lane * 7 + k];
        ew1[k] = ew[(lane + 64) * 7 + k];
    }
    float eb0v = eb[lane], eb1v = eb[lane + 64];
    for (int n = nbase; n < nbase + 8; ++n) {
        float a0 = hin[(size_t)n * HID + lane];
        float a1 = hin[(size_t)n * HID + 64 + lane];
        int beg = rp[n], end = rp[n + 1];
        for (int e = beg; e < end; ++e) {
            int s = srcp[e];
            const float* ap = eap + (size_t)e * 7;
            float t0 = eb0v, t1 = eb1v;
#pragma unroll
            for (int k = 0; k < 7; ++k) {
                float av = ap[k];
                t0 = fmaf(av, ew0[k], t0);
                t1 = fmaf(av, ew1[k], t1);
            }
            float x0 = hin[(size_t)s * HID + lane];
            float x1 = hin[(size_t)s * HID + 64 + lane];
            a0 += fmaxf(x0 + t0, 0.0f);
            a1 += fmaxf(x1 + t1, 0.0f);
        }
        float* Ap = A + (size_t)n * HID;
        Ap[lane] = a0;
        Ap[64 + lane] = a1;
    }
}

// ================= layer 0 GEMM1 (in=2 -> 128) =================
__global__ __launch_bounds__(256) void gemm1_l0_kernel(
    const float* __restrict__ aggr2,
    const float* __restrict__ w1, const float* __restrict__ b1,
    float* __restrict__ h1)
{
    int n = blockIdx.x * 256 + threadIdx.x;
    if (n >= NNODES) return;
    float x0 = aggr2[n * 2 + 0];
    float x1 = aggr2[n * 2 + 1];
    float4* out4 = (float4*)(h1 + (size_t)n * HID);
    for (int j = 0; j < HID; j += 4) {
        float4 o;
        o.x = fmaf(x1, w1[(j + 0) * 2 + 1], fmaf(x0, w1[(j + 0) * 2 + 0], b1[j + 0]));
        o.y = fmaf(x1, w1[(j + 1) * 2 + 1], fmaf(x0, w1[(j + 1) * 2 + 0], b1[j + 1]));
        o.z = fmaf(x1, w1[(j + 2) * 2 + 1], fmaf(x0, w1[(j + 2) * 2 + 0], b1[j + 2]));
        o.w = fmaf(x1, w1[(j + 3) * 2 + 1], fmaf(x0, w1[(j + 3) * 2 + 0], b1[j + 3]));
        out4[j >> 2] = o;
    }
}

// part layout (unified): part[((half*NB + blk)*2 + stat)*64 + cc], half=c>>6, cc=c&63

// ================= BN partial stats (layer 0) =================
__global__ __launch_bounds__(256) void bn_stats_part(
    const float* __restrict__ h1, float* __restrict__ part)
{
    __shared__ float ls[HID], lq[HID];
    int c = threadIdx.x & 127;
    int half = threadIdx.x >> 7;
    int base = blockIdx.x * 256;
    int end = base + 256; if (end > NNODES) end = NNODES;
    float s = 0.0f, q = 0.0f;
    for (int r = base + half; r < end; r += 2) {
        float v = h1[(size_t)r * HID + c];
        s += v;
        q = fmaf(v, v, q);
    }
    if (half) { ls[c] = s; lq[c] = q; }
    __syncthreads();
    if (!half) {
        s += ls[c]; q += lq[c];
        size_t base2 = ((size_t)((c >> 6) * NB + blockIdx.x)) * 128 + (c & 63);
        part[base2] = s;
        part[base2 + 64] = q;
    }
}

// ================= BN finalize -> scale/shift =================
__global__ __launch_bounds__(64) void bn_finalize(
    const float* __restrict__ part,
    const float* __restrict__ gamma, const float* __restrict__ beta,
    float* __restrict__ scsh)
{
    int c = blockIdx.x;            // 0..127
    int by = c >> 6, cc = c & 63;
    int lane = threadIdx.x;
    float s = 0.0f, q = 0.0f;
    for (int i = lane; i < NB; i += 64) {
        size_t base = ((size_t)(by * NB + i)) * 128;
        s += part[base + cc];
        q += part[base + 64 + cc];
    }
#pragma unroll
    for (int off = 32; off >= 1; off >>= 1) {
        s += __shfl_down(s, off);
        q += __shfl_down(q, off);
    }
    if (lane == 0) {
        const float invN = 1.0f / (float)NNODES;
        float mu = s * invN;
        float var = fmaf(-mu, mu, q * invN);
        float iv = rsqrtf(var + 1e-5f);
        float sc = gamma[c] * iv;
        scsh[c] = sc;
        scsh[HID + c] = beta[c] - mu * sc;
    }
}

// ================= GEMM1 (hidden): h1 = A @ W1^T + b1; 256x64 tile; fused BN partials =================
// grid (GB, 2); 32KB LDS (W half); thread tile 8x8; NOT in-place.
__global__ __launch_bounds__(256, 4) void gemm1_w(
    const float* __restrict__ A, const float* __restrict__ w1,
    const float* __restrict__ b1, float* __restrict__ h1,
    float* __restrict__ part)
{
    __shared__ float4 sW[64 * 32];   // 32KB
    const int t = threadIdx.x;
    const int by = blockIdx.y;       // col half
    for (int l = t; l < 64 * 32; l += 256) {
        int row = l >> 5, kk = l & 31;
        sW[row * 32 + (kk ^ (row >> 3))] = ((const float4*)w1)[(size_t)(by * 64 + row) * 32 + kk];
    }
    __syncthreads();

    const int tm = t >> 3, tn = t & 7;
    const int m0 = blockIdx.x * 256 + tm * 8;
    const int n0 = tn * 8;           // local col base (0..56)

    int gm[8];
#pragma unroll
    for (int i = 0; i < 8; ++i) {
        int r = m0 + i;
        gm[i] = r < NNODES ? r : NNODES - 1;
    }
    const float4* A4 = (const float4*)A;

    float acc[8][8];
#pragma unroll
    for (int i = 0; i < 8; ++i)
#pragma unroll
        for (int j = 0; j < 8; ++j) acc[i][j] = 0.0f;

#pragma unroll 2
    for (int kk = 0; kk < 32; ++kk) {
        float4 bfr[8];
#pragma unroll
        for (int j = 0; j < 8; ++j) bfr[j] = sW[(n0 + j) * 32 + (kk ^ tn)];
        float4 afr[8];
#pragma unroll
        for (int i = 0; i < 8; ++i) afr[i] = A4[(size_t)gm[i] * 32 + kk];
#pragma unroll
        for (int i = 0; i < 8; ++i)
#pragma unroll
            for (int j = 0; j < 8; ++j) {
                acc[i][j] = fmaf(afr[i].x, bfr[j].x, acc[i][j]);
                acc[i][j] = fmaf(afr[i].y, bfr[j].y, acc[i][j]);
                acc[i][j] = fmaf(afr[i].z, bfr[j].z, acc[i][j]);
                acc[i][j] = fmaf(afr[i].w, bfr[j].w, acc[i][j]);
            }
    }

    float bj[8];
#pragma unroll
    for (int j = 0; j < 8; ++j) bj[j] = b1[by * 64 + n0 + j];
    float s[8], q[8];
#pragma unroll
    for (int j = 0; j < 8; ++j) { s[j] = 0.0f; q[j] = 0.0f; }
#pragma unroll
    for (int i = 0; i < 8; ++i) {
        if (m0 + i < NNODES) {
            float o[8];
#pragma unroll
            for (int j = 0; j < 8; ++j) {
                float v = acc[i][j] + bj[j];
                o[j] = v;
                s[j] += v;
                q[j] = fmaf(v, v, q[j]);
            }
            float4* op = (float4*)(h1 + (size_t)(m0 + i) * HID + by * 64 + n0);
            op[0] = make_float4(o[0], o[1], o[2], o[3]);
            op[1] = make_float4(o[4], o[5], o[6], o[7]);
        }
    }
    __syncthreads();                 // all sW reads done; reuse as scratch
    float* red = (float*)sW;         // 2 * 64*33 floats, stride-33 pad
#pragma unroll
    for (int j = 0; j < 8; ++j) {
        red[(n0 + j) * 33 + tm] = s[j];
        red[2112 + (n0 + j) * 33 + tm] = q[j];
    }
    __syncthreads();
    if (t < 128) {
        int stat = t >> 6, col = t & 63;
        const float* base = red + stat * 2112 + col * 33;
        float v = 0.0f;
#pragma unroll
        for (int u = 0; u < 32; ++u) v += base[u];
        part[((size_t)(by * GB + blockIdx.x)) * 128 + stat * 64 + col] = v;
    }
}

// ================= GEMM2: hout = leaky(leaky( leaky(BN(h1)) @ W2^T + b2 )) =================
// grid (GB, 2); 32KB LDS; 256x64 tile.
__global__ __launch_bounds__(256, 4) void gemm2_w(
    const float* __restrict__ h1, const float* __restrict__ scsh,
    const float* __restrict__ w2, const float* __restrict__ b2,
    float* __restrict__ hout)
{
    __shared__ float4 sW[64 * 32];   // 32KB
    const int t = threadIdx.x;
    const int by = blockIdx.y;
    for (int l = t; l < 64 * 32; l += 256) {
        int row = l >> 5, kk = l & 31;
        sW[row * 32 + (kk ^ (row >> 3))] = ((const float4*)w2)[(size_t)(by * 64 + row) * 32 + kk];
    }
    __syncthreads();

    const int tm = t >> 3, tn = t & 7;
    const int m0 = blockIdx.x * 256 + tm * 8;
    const int n0 = tn * 8;

    int gm[8];
#pragma unroll
    for (int i = 0; i < 8; ++i) {
        int r = m0 + i;
        gm[i] = r < NNODES ? r : NNODES - 1;
    }
    const float4* A4 = (const float4*)h1;
    const float4* sc4 = (const float4*)scsh;
    const float4* sh4 = (const float4*)(scsh + HID);

    float acc[8][8];
#pragma unroll
    for (int i = 0; i < 8; ++i)
#pragma unroll
        for (int j = 0; j < 8; ++j) acc[i][j] = 0.0f;

#pragma unroll 2
    for (int kk = 0; kk < 32; ++kk) {
        float4 bfr[8];
#pragma unroll
        for (int j = 0; j < 8; ++j) bfr[j] = sW[(n0 + j) * 32 + (kk ^ tn)];
        float4 sc = sc4[kk], sh = sh4[kk];
        float4 afr[8];
#pragma unroll
        for (int i = 0; i < 8; ++i) {
            float4 v = A4[(size_t)gm[i] * 32 + kk];
            afr[i].x = leaky1(fmaf(v.x, sc.x, sh.x));
            afr[i].y = leaky1(fmaf(v.y, sc.y, sh.y));
            afr[i].z = leaky1(fmaf(v.z, sc.z, sh.z));
            afr[i].w = leaky1(fmaf(v.w, sc.w, sh.w));
        }
#pragma unroll
        for (int i = 0; i < 8; ++i)
#pragma unroll
            for (int j = 0; j < 8; ++j) {
                acc[i][j] = fmaf(afr[i].x, bfr[j].x, acc[i][j]);
                acc[i][j] = fmaf(afr[i].y, bfr[j].y, acc[i][j]);
                acc[i][j] = fmaf(afr[i].z, bfr[j].z, acc[i][j]);
                acc[i][j] = fmaf(afr[i].w, bfr[j].w, acc[i][j]);
            }
    }

    float bj[8];
#pragma unroll
    for (int j = 0; j < 8; ++j) bj[j] = b2[by * 64 + n0 + j];
#pragma unroll
    for (int i = 0; i < 8; ++i) {
        if (m0 + i < NNODES) {
            float o[8];
#pragma unroll
            for (int j = 0; j < 8; ++j) o[j] = leaky1(leaky1(acc[i][j] + bj[j]));
            float4* op = (float4*)(hout + (size_t)(m0 + i) * HID + by * 64 + n0);
            op[0] = make_float4(o[0], o[1], o[2], o[3]);
            op[1] = make_float4(o[4], o[5], o[6], o[7]);
        }
    }
}

// ================= global mean pool (batch sorted) =================
__global__ __launch_bounds__(256) void pool_kernel(
    const float* __restrict__ h, const int* __restrict__ batch,
    float* __restrict__ sums, float* __restrict__ cnt)
{
    int c = threadIdx.x & 127;
    int half = threadIdx.x >> 7;
    int base = blockIdx.x * 128 + half * 64;
    if (base >= NNODES) return;
    int end = base + 64; if (end > NNODES) end = NNODES;
    int g = batch[base];
    float acc = 0.0f, k = 0.0f;
    for (int n = base; n < end; ++n) {
        int gn = batch[n];
        if (gn != g) {
            atomicAdd(&sums[g * HID + c], acc);
            if (c == 0) atomicAdd(&cnt[g], k);
            acc = 0.0f; k = 0.0f; g = gn;
        }
        acc += h[(size_t)n * HID + c];
        k += 1.0f;
    }
    atomicAdd(&sums[g * HID + c], acc);
    if (c == 0) atomicAdd(&cnt[g], k);
}

// ================= reghead =================
__global__ __launch_bounds__(512) void reghead_kernel(
    const float* __restrict__ sums, const float* __restrict__ cnt,
    const float* __restrict__ wr, const float* __restrict__ br,
    const float* __restrict__ we, const float* __restrict__ be,
    float* __restrict__ out)
{
    __shared__ float pool[8 * HID];
    __shared__ float red[8][8];
    int g0 = blockIdx.x * 8;
    for (int i = threadIdx.x; i < 8 * HID; i += 512) {
        int g = g0 + (i >> 7);
        float c = cnt[g]; c = fmaxf(c, 1.0f);
        pool[i] = sums[g * HID + (i & 127)] / c;
    }
    __syncthreads();
    int j = threadIdx.x;
    float p[8];
#pragma unroll
    for (int g = 0; g < 8; ++g) p[g] = 0.0f;
    if (j < RHD) {
        float accs[8];
        float bjv = br[j];
#pragma unroll
        for (int g = 0; g < 8; ++g) accs[g] = bjv;
        const float4* wr4 = (const float4*)(wr + (size_t)j * HID);
        const float4* pool4 = (const float4*)pool;
        for (int k = 0; k < 32; ++k) {
            float4 w = wr4[k];
#pragma unroll
            for (int g = 0; g < 8; ++g) {
                float4 pv = pool4[g * 32 + k];
                accs[g] = fmaf(w.x, pv.x, accs[g]);
                accs[g] = fmaf(w.y, pv.y, accs[g]);
                accs[g] = fmaf(w.z, pv.z, accs[g]);
                accs[g] = fmaf(w.w, pv.w, accs[g]);
            }
        }
        float wej = we[j];
#pragma unroll
        for (int g = 0; g < 8; ++g) p[g] = leaky1(accs[g]) * wej;
    }
    int lane = threadIdx.x & 63, wid = threadIdx.x >> 6;
#pragma unroll
    for (int g = 0; g < 8; ++g) {
        float v = p[g];
        v += __shfl_down(v, 32); v += __shfl_down(v, 16); v += __shfl_down(v, 8);
        v += __shfl_down(v, 4);  v += __shfl_down(v, 2);  v += __shfl_down(v, 1);
        if (lane == 0) red[g][wid] = v;
    }
    __syncthreads();
    if (threadIdx.x < 8) {
        float sv = be[0];
#pragma unroll
        for (int w = 0; w < 8; ++w) sv += red[threadIdx.x][w];
        out[g0 + threadIdx.x] = sv;
    }
}

extern "C" void kernel_launch(void* const* d_in, const int* in_sizes, int n_in,
                              void* d_out, int out_size, void* d_ws, size_t ws_size,
                              hipStream_t stream)
{
    const float* x     = (const float*)d_in[0];
    const int*   ei    = (const int*)d_in[1];
    const int*   batch = (const int*)d_in[2];
    const float* ea    = (const float*)d_in[3];
    const float* ew0   = (const float*)d_in[4];
    const float* eb0   = (const float*)d_in[5];
    const float* w10   = (const float*)d_in[6];
    const float* b10   = (const float*)d_in[7];
    const float* g0v   = (const float*)d_in[8];
    const float* be0   = (const float*)d_in[9];
    const float* w20   = (const float*)d_in[10];
    const float* b20   = (const float*)d_in[11];
    const float* ewS   = (const float*)d_in[12];
    const float* ebS   = (const float*)d_in[13];
    const float* w1S   = (const float*)d_in[14];
    const float* b1S   = (const float*)d_in[15];
    const float* gS    = (const float*)d_in[16];
    const float* beS   = (const float*)d_in[17];
    const float* w2S   = (const float*)d_in[18];
    const float* b2S   = (const float*)d_in[19];
    const float* wr    = (const float*)d_in[20];
    const float* br    = (const float*)d_in[21];
    const float* we    = (const float*)d_in[22];
    const float* be_   = (const float*)d_in[23];

    float* ws    = (float*)d_ws;
    float* buf0  = ws;                                   // N*128
    float* buf1  = buf0 + (size_t)NNODES * HID;          // N*128
    float* part  = buf1 + (size_t)NNODES * HID;          // 2*GB*128
    float* scsh  = part + 2ull * GB * 128;               // 256
    float* sums  = scsh + 256;                           // 64*128
    float* cnt   = sums + NGRAPH * HID;                  // 64
    float* aggr2 = cnt + NGRAPH;                         // N*2
    float* eap   = aggr2 + (size_t)NNODES * 2;           // E*7
    int*   deg    = (int*)(eap + (size_t)NEDGES * 7);    // N
    int*   cursor = deg + NNODES;                        // N
    int*   bsum   = cursor + NNODES;                     // 512
    int*   rp     = bsum + 512;                          // N+1
    int*   eid    = rp + NNODES + 1;                     // E
    int*   srcp   = eid + NEDGES;                        // E
    float* out   = (float*)d_out;

    dim3 ggrid(GB, 2);

    // ---- CSR build (deterministic; once per launch) ----
    hipMemsetAsync(deg, 0, (size_t)NNODES * sizeof(int), stream);
    hist_kernel<<<EB, 256, 0, stream>>>(ei, deg);
    scan_blk<<<NB, 256, 0, stream>>>(deg, rp, bsum);
    scan_bsum<<<1, 512, 0, stream>>>(bsum, NB);
    finalize_rp<<<NB, 256, 0, stream>>>(deg, bsum, rp, cursor);
    scatter_kernel<<<EB, 256, 0, stream>>>(ei, cursor, eid);
    seg_sort<<<NB, 256, 0, stream>>>(rp, eid);
    permute_kernel<<<EB, 256, 0, stream>>>(eid, ei, ea, srcp, eap);

    // ---- layer 0: h1 -> buf0, h_out -> buf1 ----
    aggregate0_kernel<<<NB, 256, 0, stream>>>(x, rp, srcp, eap, ew0, eb0, aggr2);
    gemm1_l0_kernel<<<NB, 256, 0, stream>>>(aggr2, w10, b10, buf0);
    bn_stats_part<<<NB, 256, 0, stream>>>(buf0, part);
    bn_finalize<<<HID, 64, 0, stream>>>(part, g0v, be0, scsh);
    gemm2_w<<<ggrid, 256, 0, stream>>>(buf0, scsh, w20, b20, buf1);

    // ---- hidden layers: ping-pong buf0/buf1 ----
    int cur = 1;   // h lives in buf[cur]
    float* bufs[2] = { buf0, buf1 };
    for (int i = 0; i < 3; ++i) {
        float* hin  = bufs[cur];
        float* hoth = bufs[cur ^ 1];
        aggregate_kernel<<<NNODES / 32, 256, 0, stream>>>(hin, rp, srcp, eap,
            ewS + (size_t)i * HID * 7, ebS + (size_t)i * HID, hoth);      // A -> other
        gemm1_w<<<ggrid, 256, 0, stream>>>(hoth,
            w1S + (size_t)i * HID * HID, b1S + (size_t)i * HID, hin, part); // h1 -> cur (h dead)
        bn_finalize<<<HID, 64, 0, stream>>>(part,
            gS + (size_t)i * HID, beS + (size_t)i * HID, scsh);
        gemm2_w<<<ggrid, 256, 0, stream>>>(hin, scsh,
            w2S + (size_t)i * HID * HID, b2S + (size_t)i * HID, hoth);    // h_out -> other
        cur ^= 1;
    }

    // ---- pooling + reghead ----
    hipMemsetAsync(sums, 0, (size_t)(NGRAPH * HID + NGRAPH) * sizeof(float), stream);
    pool_kernel<<<(NNODES + 127) / 128, 256, 0, stream>>>(bufs[cur], batch, sums, cnt);
    reghead_kernel<<<NGRAPH / 8, 512, 0, stream>>>(sums, cnt, wr, br, we, be_, out);
}

// Round 6
// 1450.818 us; speedup vs baseline: 2.0376x; 2.0376x over previous
//
#include <hip/hip_runtime.h>

#define NNODES 100000
#define NEDGES 600000
#define NGRAPH 64
#define HID 128
#define RHD 500
#define NB ((NNODES + 255) / 256)            // 391
#define EB ((NEDGES + 255) / 256)            // 2344
#define GROWS 128
#define GGRID ((NNODES + GROWS - 1) / GROWS) // 782

__device__ __forceinline__ float leaky1(float x) { return x >= 0.0f ? x : 0.01f * x; }

// ================= CSR build (deterministic) =================
__global__ __launch_bounds__(256) void hist_kernel(
    const int* __restrict__ ei, int* __restrict__ deg)
{
    int e = blockIdx.x * 256 + threadIdx.x;
    if (e < NEDGES) atomicAdd(&deg[ei[NEDGES + e]], 1);
}

__global__ __launch_bounds__(256) void scan_blk(
    const int* __restrict__ deg, int* __restrict__ incl, int* __restrict__ bsum)
{
    __shared__ int s[256];
    int t = threadIdx.x;
    int n = blockIdx.x * 256 + t;
    int v = (n < NNODES) ? deg[n] : 0;
    int x = v;
    s[t] = x;
    __syncthreads();
    for (int off = 1; off < 256; off <<= 1) {
        int y = (t >= off) ? s[t - off] : 0;
        __syncthreads();
        x += y; s[t] = x;
        __syncthreads();
    }
    if (n < NNODES) incl[n] = x;
    if (t == 255) bsum[blockIdx.x] = x;
}

__global__ __launch_bounds__(512) void scan_bsum(int* __restrict__ bsum, int nblk)
{
    __shared__ int s[512];
    int t = threadIdx.x;
    int v = (t < nblk) ? bsum[t] : 0;
    int x = v;
    s[t] = x;
    __syncthreads();
    for (int off = 1; off < 512; off <<= 1) {
        int y = (t >= off) ? s[t - off] : 0;
        __syncthreads();
        x += y; s[t] = x;
        __syncthreads();
    }
    if (t < nblk) bsum[t] = x - v;   // exclusive
}

__global__ __launch_bounds__(256) void finalize_rp(
    const int* __restrict__ deg, const int* __restrict__ bsum,
    int* __restrict__ rp, int* __restrict__ cursor)
{
    int n = blockIdx.x * 256 + threadIdx.x;
    if (n >= NNODES) return;
    int ig = rp[n] + bsum[blockIdx.x];   // global inclusive
    int st = ig - deg[n];
    rp[n] = st;
    cursor[n] = st;
    if (n == NNODES - 1) rp[NNODES] = ig;
}

__global__ __launch_bounds__(256) void scatter_kernel(
    const int* __restrict__ ei, int* __restrict__ cursor, int* __restrict__ eid)
{
    int e = blockIdx.x * 256 + threadIdx.x;
    if (e >= NEDGES) return;
    int d = ei[NEDGES + e];
    int pos = atomicAdd(&cursor[d], 1);
    eid[pos] = e;
}

__global__ __launch_bounds__(256) void seg_sort(
    const int* __restrict__ rp, int* __restrict__ eid)
{
    int n = blockIdx.x * 256 + threadIdx.x;
    if (n >= NNODES) return;
    int beg = rp[n], end = rp[n + 1];
    for (int i = beg + 1; i < end; ++i) {
        int key = eid[i];
        int j = i - 1;
        while (j >= beg && eid[j] > key) { eid[j + 1] = eid[j]; --j; }
        eid[j + 1] = key;
    }
}

__global__ __launch_bounds__(256) void permute_kernel(
    const int* __restrict__ eid, const int* __restrict__ ei,
    const float* __restrict__ ea, int* __restrict__ srcp, float* __restrict__ eap)
{
    int p = blockIdx.x * 256 + threadIdx.x;
    if (p >= NEDGES) return;
    int id = eid[p];
    srcp[p] = ei[id];
    const float* s = ea + (size_t)id * 7;
    float* d = eap + (size_t)p * 7;
#pragma unroll
    for (int k = 0; k < 7; ++k) d[k] = s[k];
}

// ================= layer 0 aggregate (d=2) =================
__global__ __launch_bounds__(256) void aggregate0_kernel(
    const float* __restrict__ x, const int* __restrict__ rp,
    const int* __restrict__ srcp, const float* __restrict__ eap,
    const float* __restrict__ ew, const float* __restrict__ eb,
    float* __restrict__ aggr2)
{
    int n = blockIdx.x * 256 + threadIdx.x;
    if (n >= NNODES) return;
    float w0[7], w1[7];
#pragma unroll
    for (int k = 0; k < 7; ++k) { w0[k] = ew[k]; w1[k] = ew[7 + k]; }
    float e0b = eb[0], e1b = eb[1];
    float a0 = x[n * 2 + 0], a1 = x[n * 2 + 1];
    int beg = rp[n], end = rp[n + 1];
    for (int e = beg; e < end; ++e) {
        int s = srcp[e];
        const float* ap = eap + (size_t)e * 7;
        float t0 = e0b, t1 = e1b;
#pragma unroll
        for (int k = 0; k < 7; ++k) {
            float av = ap[k];
            t0 = fmaf(av, w0[k], t0);
            t1 = fmaf(av, w1[k], t1);
        }
        a0 += fmaxf(x[s * 2 + 0] + t0, 0.0f);
        a1 += fmaxf(x[s * 2 + 1] + t1, 0.0f);
    }
    aggr2[n * 2 + 0] = a0;
    aggr2[n * 2 + 1] = a1;
}

// ================= hidden aggregate (d=128): one wave per 8 nodes =================
__global__ __launch_bounds__(256) void aggregate_kernel(
    const float* __restrict__ hin, const int* __restrict__ rp,
    const int* __restrict__ srcp, const float* __restrict__ eap,
    const float* __restrict__ ew, const float* __restrict__ eb,
    float* __restrict__ A)
{
    int lane = threadIdx.x & 63;
    int w = threadIdx.x >> 6;
    int nbase = blockIdx.x * 32 + w * 8;
    float ew0[7], ew1[7];
#pragma unroll
    for (int k = 0; k < 7; ++k) {
        ew0[k] = ew[lane * 7 + k];
        ew1[k] = ew[(lane + 64) * 7 + k];
    }
    float eb0v = eb[lane], eb1v = eb[lane + 64];
    for (int n = nbase; n < nbase + 8; ++n) {
        float a0 = hin[(size_t)n * HID + lane];
        float a1 = hin[(size_t)n * HID + 64 + lane];
        int beg = rp[n], end = rp[n + 1];
        for (int e = beg; e < end; ++e) {
            int s = srcp[e];
            const float* ap = eap + (size_t)e * 7;
            float t0 = eb0v, t1 = eb1v;
#pragma unroll
            for (int k = 0; k < 7; ++k) {
                float av = ap[k];
                t0 = fmaf(av, ew0[k], t0);
                t1 = fmaf(av, ew1[k], t1);
            }
            float x0 = hin[(size_t)s * HID + lane];
            float x1 = hin[(size_t)s * HID + 64 + lane];
            a0 += fmaxf(x0 + t0, 0.0f);
            a1 += fmaxf(x1 + t1, 0.0f);
        }
        float* Ap = A + (size_t)n * HID;
        Ap[lane] = a0;
        Ap[64 + lane] = a1;
    }
}

// ================= layer 0 GEMM1 (in=2 -> 128) =================
__global__ __launch_bounds__(256) void gemm1_l0_kernel(
    const float* __restrict__ aggr2,
    const float* __restrict__ w1, const float* __restrict__ b1,
    float* __restrict__ h1)
{
    int n = blockIdx.x * 256 + threadIdx.x;
    if (n >= NNODES) return;
    float x0 = aggr2[n * 2 + 0];
    float x1 = aggr2[n * 2 + 1];
    float4* out4 = (float4*)(h1 + (size_t)n * HID);
    for (int j = 0; j < HID; j += 4) {
        float4 o;
        o.x = fmaf(x1, w1[(j + 0) * 2 + 1], fmaf(x0, w1[(j + 0) * 2 + 0], b1[j + 0]));
        o.y = fmaf(x1, w1[(j + 1) * 2 + 1], fmaf(x0, w1[(j + 1) * 2 + 0], b1[j + 1]));
        o.z = fmaf(x1, w1[(j + 2) * 2 + 1], fmaf(x0, w1[(j + 2) * 2 + 0], b1[j + 2]));
        o.w = fmaf(x1, w1[(j + 3) * 2 + 1], fmaf(x0, w1[(j + 3) * 2 + 0], b1[j + 3]));
        out4[j >> 2] = o;
    }
}

// part layout: part[blk*256 + c] = sum, part[blk*256 + 128 + c] = sumsq

// ================= BN partial stats (layer 0) =================
__global__ __launch_bounds__(256) void bn_stats_part(
    const float* __restrict__ h1, float* __restrict__ part)
{
    __shared__ float ls[HID], lq[HID];
    int c = threadIdx.x & 127;
    int half = threadIdx.x >> 7;
    int base = blockIdx.x * 256;
    int end = base + 256; if (end > NNODES) end = NNODES;
    float s = 0.0f, q = 0.0f;
    for (int r = base + half; r < end; r += 2) {
        float v = h1[(size_t)r * HID + c];
        s += v;
        q = fmaf(v, v, q);
    }
    if (half) { ls[c] = s; lq[c] = q; }
    __syncthreads();
    if (!half) {
        s += ls[c]; q += lq[c];
        part[(size_t)blockIdx.x * 256 + c] = s;
        part[(size_t)blockIdx.x * 256 + 128 + c] = q;
    }
}

// ================= BN finalize -> scale/shift =================
__global__ __launch_bounds__(64) void bn_finalize(
    const float* __restrict__ part, int nblk,
    const float* __restrict__ gamma, const float* __restrict__ beta,
    float* __restrict__ scsh)
{
    int c = blockIdx.x;            // 0..127
    int lane = threadIdx.x;
    float s = 0.0f, q = 0.0f;
    for (int i = lane; i < nblk; i += 64) {
        s += part[(size_t)i * 256 + c];
        q += part[(size_t)i * 256 + 128 + c];
    }
#pragma unroll
    for (int off = 32; off >= 1; off >>= 1) {
        s += __shfl_down(s, off);
        q += __shfl_down(q, off);
    }
    if (lane == 0) {
        const float invN = 1.0f / (float)NNODES;
        float mu = s * invN;
        float var = fmaf(-mu, mu, q * invN);
        float iv = rsqrtf(var + 1e-5f);
        float sc = gamma[c] * iv;
        scsh[c] = sc;
        scsh[HID + c] = beta[c] - mu * sc;
    }
}

// ================= GEMM1 (hidden): h1 = A @ W1^T + b1; A-tile in LDS; fused BN partials =================
// 512 threads, tile 128 rows x 128 cols, thread tile 8x4. A staged ONCE to LDS
// (xor-swizzled, conflict-free), W read via L1 (8KB/4kk working set). No K-loop barriers.
__global__ __launch_bounds__(512) void gemm1_w(
    const float* __restrict__ A, const float* __restrict__ w1,
    const float* __restrict__ b1, float* __restrict__ h1,
    float* __restrict__ part)
{
    __shared__ float4 sA[GROWS * 32];   // 64KB
    const int t = threadIdx.x;
    const int mb = blockIdx.x * GROWS;
    const float4* Ag = (const float4*)A + (size_t)mb * 32;
#pragma unroll
    for (int k = 0; k < 8; ++k) {
        int idx = k * 512 + t;
        int row = idx >> 5, col = idx & 31;
        float4 v = make_float4(0.f, 0.f, 0.f, 0.f);
        if (mb + row < NNODES) v = Ag[idx];
        sA[row * 32 + (col ^ ((row >> 3) & 7))] = v;
    }
    __syncthreads();

    const int tm = t >> 5, tn = t & 31;      // tm: 16 row groups, tn: 32 col groups
    const int swz = tm & 7;
    const float4* wp = (const float4*)w1 + (size_t)tn * 4 * 32;

    float acc[8][4];
#pragma unroll
    for (int i = 0; i < 8; ++i)
#pragma unroll
        for (int j = 0; j < 4; ++j) acc[i][j] = 0.0f;

#pragma unroll 4
    for (int kk = 0; kk < 32; ++kk) {
        float4 bfr[4];
#pragma unroll
        for (int j = 0; j < 4; ++j) bfr[j] = wp[j * 32 + kk];
        float4 afr[8];
#pragma unroll
        for (int i = 0; i < 8; ++i) afr[i] = sA[(tm * 8 + i) * 32 + (kk ^ swz)];
#pragma unroll
        for (int i = 0; i < 8; ++i)
#pragma unroll
            for (int j = 0; j < 4; ++j) {
                acc[i][j] = fmaf(afr[i].x, bfr[j].x, acc[i][j]);
                acc[i][j] = fmaf(afr[i].y, bfr[j].y, acc[i][j]);
                acc[i][j] = fmaf(afr[i].z, bfr[j].z, acc[i][j]);
                acc[i][j] = fmaf(afr[i].w, bfr[j].w, acc[i][j]);
            }
    }

    float bj[4];
#pragma unroll
    for (int j = 0; j < 4; ++j) bj[j] = b1[tn * 4 + j];
    float s[4] = {0.f, 0.f, 0.f, 0.f}, q[4] = {0.f, 0.f, 0.f, 0.f};
#pragma unroll
    for (int i = 0; i < 8; ++i) {
        int gr = mb + tm * 8 + i;
        if (gr < NNODES) {
            float o[4];
#pragma unroll
            for (int j = 0; j < 4; ++j) {
                float v = acc[i][j] + bj[j];
                o[j] = v;
                s[j] += v;
                q[j] = fmaf(v, v, q[j]);
            }
            *(float4*)(h1 + (size_t)gr * HID + tn * 4) = make_float4(o[0], o[1], o[2], o[3]);
        }
    }
    __syncthreads();                  // done with sA; reuse as scratch
    float* red = (float*)sA;          // 2 * 128*17 floats = 17KB
#pragma unroll
    for (int j = 0; j < 4; ++j) {
        red[(tn * 4 + j) * 17 + tm] = s[j];
        red[2176 + (tn * 4 + j) * 17 + tm] = q[j];
    }
    __syncthreads();
    if (t < 256) {
        int stat = t >> 7, col = t & 127;
        const float* bp = red + stat * 2176 + col * 17;
        float v = 0.0f;
#pragma unroll
        for (int u = 0; u < 16; ++u) v += bp[u];
        part[(size_t)blockIdx.x * 256 + stat * 128 + col] = v;
    }
}

// ================= GEMM2: hout = leaky(leaky( leaky(BN(h1)) @ W2^T + b2 )) =================
// BN+leaky fused into LDS staging transform.
__global__ __launch_bounds__(512) void gemm2_w(
    const float* __restrict__ h1, const float* __restrict__ scsh,
    const float* __restrict__ w2, const float* __restrict__ b2,
    float* __restrict__ hout)
{
    __shared__ float4 sA[GROWS * 32];   // 64KB
    const int t = threadIdx.x;
    const int mb = blockIdx.x * GROWS;
    const float4* Ag = (const float4*)h1 + (size_t)mb * 32;
    const float4* sc4 = (const float4*)scsh;
    const float4* sh4 = (const float4*)(scsh + HID);
#pragma unroll
    for (int k = 0; k < 8; ++k) {
        int idx = k * 512 + t;
        int row = idx >> 5, col = idx & 31;
        float4 o = make_float4(0.f, 0.f, 0.f, 0.f);
        if (mb + row < NNODES) {
            float4 v = Ag[idx];
            float4 sc = sc4[col], sh = sh4[col];
            o.x = leaky1(fmaf(v.x, sc.x, sh.x));
            o.y = leaky1(fmaf(v.y, sc.y, sh.y));
            o.z = leaky1(fmaf(v.z, sc.z, sh.z));
            o.w = leaky1(fmaf(v.w, sc.w, sh.w));
        }
        sA[row * 32 + (col ^ ((row >> 3) & 7))] = o;
    }
    __syncthreads();

    const int tm = t >> 5, tn = t & 31;
    const int swz = tm & 7;
    const float4* wp = (const float4*)w2 + (size_t)tn * 4 * 32;

    float acc[8][4];
#pragma unroll
    for (int i = 0; i < 8; ++i)
#pragma unroll
        for (int j = 0; j < 4; ++j) acc[i][j] = 0.0f;

#pragma unroll 4
    for (int kk = 0; kk < 32; ++kk) {
        float4 bfr[4];
#pragma unroll
        for (int j = 0; j < 4; ++j) bfr[j] = wp[j * 32 + kk];
        float4 afr[8];
#pragma unroll
        for (int i = 0; i < 8; ++i) afr[i] = sA[(tm * 8 + i) * 32 + (kk ^ swz)];
#pragma unroll
        for (int i = 0; i < 8; ++i)
#pragma unroll
            for (int j = 0; j < 4; ++j) {
                acc[i][j] = fmaf(afr[i].x, bfr[j].x, acc[i][j]);
                acc[i][j] = fmaf(afr[i].y, bfr[j].y, acc[i][j]);
                acc[i][j] = fmaf(afr[i].z, bfr[j].z, acc[i][j]);
                acc[i][j] = fmaf(afr[i].w, bfr[j].w, acc[i][j]);
            }
    }

    float bj[4];
#pragma unroll
    for (int j = 0; j < 4; ++j) bj[j] = b2[tn * 4 + j];
#pragma unroll
    for (int i = 0; i < 8; ++i) {
        int gr = mb + tm * 8 + i;
        if (gr < NNODES) {
            float o[4];
#pragma unroll
            for (int j = 0; j < 4; ++j) o[j] = leaky1(leaky1(acc[i][j] + bj[j]));
            *(float4*)(hout + (size_t)gr * HID + tn * 4) = make_float4(o[0], o[1], o[2], o[3]);
        }
    }
}

// ================= global mean pool (batch sorted) =================
__global__ __launch_bounds__(256) void pool_kernel(
    const float* __restrict__ h, const int* __restrict__ batch,
    float* __restrict__ sums, float* __restrict__ cnt)
{
    int c = threadIdx.x & 127;
    int half = threadIdx.x >> 7;
    int base = blockIdx.x * 128 + half * 64;
    if (base >= NNODES) return;
    int end = base + 64; if (end > NNODES) end = NNODES;
    int g = batch[base];
    float acc = 0.0f, k = 0.0f;
    for (int n = base; n < end; ++n) {
        int gn = batch[n];
        if (gn != g) {
            atomicAdd(&sums[g * HID + c], acc);
            if (c == 0) atomicAdd(&cnt[g], k);
            acc = 0.0f; k = 0.0f; g = gn;
        }
        acc += h[(size_t)n * HID + c];
        k += 1.0f;
    }
    atomicAdd(&sums[g * HID + c], acc);
    if (c == 0) atomicAdd(&cnt[g], k);
}

// ================= reghead =================
__global__ __launch_bounds__(512) void reghead_kernel(
    const float* __restrict__ sums, const float* __restrict__ cnt,
    const float* __restrict__ wr, const float* __restrict__ br,
    const float* __restrict__ we, const float* __restrict__ be,
    float* __restrict__ out)
{
    __shared__ float pool[8 * HID];
    __shared__ float red[8][8];
    int g0 = blockIdx.x * 8;
    for (int i = threadIdx.x; i < 8 * HID; i += 512) {
        int g = g0 + (i >> 7);
        float c = cnt[g]; c = fmaxf(c, 1.0f);
        pool[i] = sums[g * HID + (i & 127)] / c;
    }
    __syncthreads();
    int j = threadIdx.x;
    float p[8];
#pragma unroll
    for (int g = 0; g < 8; ++g) p[g] = 0.0f;
    if (j < RHD) {
        float accs[8];
        float bjv = br[j];
#pragma unroll
        for (int g = 0; g < 8; ++g) accs[g] = bjv;
        const float4* wr4 = (const float4*)(wr + (size_t)j * HID);
        const float4* pool4 = (const float4*)pool;
        for (int k = 0; k < 32; ++k) {
            float4 w = wr4[k];
#pragma unroll
            for (int g = 0; g < 8; ++g) {
                float4 pv = pool4[g * 32 + k];
                accs[g] = fmaf(w.x, pv.x, accs[g]);
                accs[g] = fmaf(w.y, pv.y, accs[g]);
                accs[g] = fmaf(w.z, pv.z, accs[g]);
                accs[g] = fmaf(w.w, pv.w, accs[g]);
            }
        }
        float wej = we[j];
#pragma unroll
        for (int g = 0; g < 8; ++g) p[g] = leaky1(accs[g]) * wej;
    }
    int lane = threadIdx.x & 63, wid = threadIdx.x >> 6;
#pragma unroll
    for (int g = 0; g < 8; ++g) {
        float v = p[g];
        v += __shfl_down(v, 32); v += __shfl_down(v, 16); v += __shfl_down(v, 8);
        v += __shfl_down(v, 4);  v += __shfl_down(v, 2);  v += __shfl_down(v, 1);
        if (lane == 0) red[g][wid] = v;
    }
    __syncthreads();
    if (threadIdx.x < 8) {
        float sv = be[0];
#pragma unroll
        for (int w = 0; w < 8; ++w) sv += red[threadIdx.x][w];
        out[g0 + threadIdx.x] = sv;
    }
}

extern "C" void kernel_launch(void* const* d_in, const int* in_sizes, int n_in,
                              void* d_out, int out_size, void* d_ws, size_t ws_size,
                              hipStream_t stream)
{
    const float* x     = (const float*)d_in[0];
    const int*   ei    = (const int*)d_in[1];
    const int*   batch = (const int*)d_in[2];
    const float* ea    = (const float*)d_in[3];
    const float* ew0   = (const float*)d_in[4];
    const float* eb0   = (const float*)d_in[5];
    const float* w10   = (const float*)d_in[6];
    const float* b10   = (const float*)d_in[7];
    const float* g0v   = (const float*)d_in[8];
    const float* be0   = (const float*)d_in[9];
    const float* w20   = (const float*)d_in[10];
    const float* b20   = (const float*)d_in[11];
    const float* ewS   = (const float*)d_in[12];
    const float* ebS   = (const float*)d_in[13];
    const float* w1S   = (const float*)d_in[14];
    const float* b1S   = (const float*)d_in[15];
    const float* gS    = (const float*)d_in[16];
    const float* beS   = (const float*)d_in[17];
    const float* w2S   = (const float*)d_in[18];
    const float* b2S   = (const float*)d_in[19];
    const float* wr    = (const float*)d_in[20];
    const float* br    = (const float*)d_in[21];
    const float* we    = (const float*)d_in[22];
    const float* be_   = (const float*)d_in[23];

    float* ws    = (float*)d_ws;
    float* buf0  = ws;                                   // N*128
    float* buf1  = buf0 + (size_t)NNODES * HID;          // N*128
    float* part  = buf1 + (size_t)NNODES * HID;          // GGRID*256
    float* scsh  = part + (size_t)GGRID * 256;           // 256
    float* sums  = scsh + 256;                           // 64*128
    float* cnt   = sums + NGRAPH * HID;                  // 64
    float* aggr2 = cnt + NGRAPH;                         // N*2
    float* eap   = aggr2 + (size_t)NNODES * 2;           // E*7
    int*   deg    = (int*)(eap + (size_t)NEDGES * 7);    // N
    int*   cursor = deg + NNODES;                        // N
    int*   bsum   = cursor + NNODES;                     // 512
    int*   rp     = bsum + 512;                          // N+1
    int*   eid    = rp + NNODES + 1;                     // E
    int*   srcp   = eid + NEDGES;                        // E
    float* out   = (float*)d_out;

    // ---- CSR build (deterministic; once per launch) ----
    hipMemsetAsync(deg, 0, (size_t)NNODES * sizeof(int), stream);
    hist_kernel<<<EB, 256, 0, stream>>>(ei, deg);
    scan_blk<<<NB, 256, 0, stream>>>(deg, rp, bsum);
    scan_bsum<<<1, 512, 0, stream>>>(bsum, NB);
    finalize_rp<<<NB, 256, 0, stream>>>(deg, bsum, rp, cursor);
    scatter_kernel<<<EB, 256, 0, stream>>>(ei, cursor, eid);
    seg_sort<<<NB, 256, 0, stream>>>(rp, eid);
    permute_kernel<<<EB, 256, 0, stream>>>(eid, ei, ea, srcp, eap);

    // ---- layer 0: h1 -> buf0, h_out -> buf1 ----
    aggregate0_kernel<<<NB, 256, 0, stream>>>(x, rp, srcp, eap, ew0, eb0, aggr2);
    gemm1_l0_kernel<<<NB, 256, 0, stream>>>(aggr2, w10, b10, buf0);
    bn_stats_part<<<NB, 256, 0, stream>>>(buf0, part);
    bn_finalize<<<HID, 64, 0, stream>>>(part, NB, g0v, be0, scsh);
    gemm2_w<<<GGRID, 512, 0, stream>>>(buf0, scsh, w20, b20, buf1);

    // ---- hidden layers: ping-pong buf0/buf1 ----
    int cur = 1;   // h lives in buf[cur]
    float* bufs[2] = { buf0, buf1 };
    for (int i = 0; i < 3; ++i) {
        float* hin  = bufs[cur];
        float* hoth = bufs[cur ^ 1];
        aggregate_kernel<<<NNODES / 32, 256, 0, stream>>>(hin, rp, srcp, eap,
            ewS + (size_t)i * HID * 7, ebS + (size_t)i * HID, hoth);        // A -> other
        gemm1_w<<<GGRID, 512, 0, stream>>>(hoth,
            w1S + (size_t)i * HID * HID, b1S + (size_t)i * HID, hin, part); // h1 -> cur (h dead)
        bn_finalize<<<HID, 64, 0, stream>>>(part, GGRID,
            gS + (size_t)i * HID, beS + (size_t)i * HID, scsh);
        gemm2_w<<<GGRID, 512, 0, stream>>>(hin, scsh,
            w2S + (size_t)i * HID * HID, b2S + (size_t)i * HID, hoth);      // h_out -> other
        cur ^= 1;
    }

    // ---- pooling + reghead ----
    hipMemsetAsync(sums, 0, (size_t)(NGRAPH * HID + NGRAPH) * sizeof(float), stream);
    pool_kernel<<<(NNODES + 127) / 128, 256, 0, stream>>>(bufs[cur], batch, sums, cnt);
    reghead_kernel<<<NGRAPH / 8, 512, 0, stream>>>(sums, cnt, wr, br, we, be_, out);
}